// Round 15
// baseline (167.691 us; speedup 1.0000x reference)
//
#include <hip/hip_runtime.h>
#include <hip/hip_cooperative_groups.h>

namespace cg = cooperative_groups;

#define IN_F 1024
#define ASS 100000
#define OUT_F 1024
#define TOTAL (IN_F + ASS + OUT_F)  // 102048
#define ASS0 IN_F
#define OUT0 (IN_F + ASS)
#define NDST (ASS + OUT_F)  // 101024 destinations, node = ASS0 + d
#define NUM_ROUNDS 24

#define BIN_SZ 512  // dst nodes per bin
#define BIN_SH 9
#define BIN_MK 511
#define NBINS ((NDST + BIN_SZ - 1) / BIN_SZ)  // 198
#define NCON 512    // construction blocks
#define CON_T 1024  // construction threads per block
#define SPLIT 8     // sub-blocks per bin in round 1
#define NBM32 3136  // level-0 bitmask words (>= ASS/32)

typedef int i4v __attribute__((ext_vector_type(4)));
typedef float f4v __attribute__((ext_vector_type(4)));
typedef unsigned int u2v __attribute__((ext_vector_type(2)));

// ---------------------------------------------------------------------------
// Each assoc neuron fires exactly once at BFS level L(u). Level-0 set (input
// receivers) is known BEFORE edge construction, so kc splits each bin's
// fixed-cap region bidirectionally:
//   A0  (src level-0, fires at r0): {dstoff, tv[src]*w} -- contribution
//       precomputed, filled UP from b*cap. Round 0 = pure stream, no gathers.
//   REST (everything else): {src<<9|dstoff, w}, filled DOWN from (b+1)*cap.
// ltv[node] = {lev, tanh snapshot at fire time} packed 8B.
// Round 0: kRa, one block per bin (stream + LDS slice + epilogue).
// Round 1: kRe (NBINS*8 blocks over REST, collects survivors: edges whose
// src is still unreached -- the only ones that can fire at r>=2) + kRn merge.
// Rounds 2..23 + output write: ONE cooperative kTail over survivors
// (grid.sync per round, uniform early break; overflow -> REST fallback).
// Torn-8B-read safety: ltv writes only transition lev 255->r+1, so a reader
// checking lev==r can never pair a stale tv with a matching lev.
// ---------------------------------------------------------------------------

__global__ __launch_bounds__(256) void kz(float* mem, u2v* ltv, int* flags,
                                          int* cur0, int* cur1, int* scur,
                                          unsigned* bm, int cap, int scap) {
  int i = blockIdx.x * 256 + threadIdx.x;
  int gs = gridDim.x * 256;
  u2v init;
  init.x = 255u;
  init.y = 0u;
  for (int k = i; k < TOTAL; k += gs) {
    mem[k] = 0.f;
    ltv[k] = init;
  }
  for (int k = i; k < NBINS; k += gs) {
    cur0[k] = k * cap;
    cur1[k] = (k + 1) * cap;
    scur[k] = k * scap;
  }
  for (int k = i; k < NBM32; k += gs) bm[k] = 0u;
  if (i < 32) flags[i] = 0;
}

__global__ __launch_bounds__(256) void ki(const float* __restrict__ x,
                                          const float* __restrict__ iw,
                                          const int* __restrict__ ies,
                                          const int* __restrict__ ied, int E_in,
                                          float* mem, unsigned int* ltv_raw,
                                          unsigned* bm) {
  int e = blockIdx.x * 256 + threadIdx.x;
  if (e < E_in) {
    int d = ied[e];  // always an assoc node by construction
    atomicAdd(&mem[d], x[ies[e]] * iw[e]);
    ltv_raw[2 * d] = 0u;  // lev = 0; benign race, all writers store 0
    int b = d - ASS0;
    atomicOr(&bm[b >> 5], 1u << (b & 31));
  }
}

// snapshot level-0 frontier: tv = tanh(mem), mem = 0
__global__ __launch_bounds__(256) void kp(float* mem, u2v* ltv) {
  int i = blockIdx.x * 256 + threadIdx.x;
  if (i < ASS) {
    int node = ASS0 + i;
    u2v lt = ltv[node];
    if (lt.x == 0u) {
      lt.y = __float_as_uint(tanhf(mem[node]));
      ltv[node] = lt;
      mem[node] = 0.f;
    }
  }
}

// construction: bitmask-classified histogram -> bidirectional reserve ->
// scatter. A0 contributions computed inline (ltv gather, L2-hot 816KB).
__global__ __launch_bounds__(CON_T) void kc(const int* __restrict__ aes,
                                            const int* __restrict__ aed,
                                            const float* __restrict__ aw,
                                            int E_a, int* cur0, int* cur1,
                                            const u2v* __restrict__ ltv,
                                            const unsigned* __restrict__ bm,
                                            u2v* __restrict__ csr) {
  __shared__ unsigned sbm[NBM32];
  __shared__ int hA[NBINS], hR[NBINS], cA[NBINS], cR[NBINS];
  for (int k = threadIdx.x; k < NBM32; k += CON_T) sbm[k] = bm[k];
  for (int b = threadIdx.x; b < NBINS; b += CON_T) {
    hA[b] = 0;
    hR[b] = 0;
  }
  __syncthreads();
  const i4v* aed4 = (const i4v*)aed;
  const i4v* aes4 = (const i4v*)aes;
  const f4v* aw4 = (const f4v*)aw;
  int nv4 = E_a >> 2;
  int stride = gridDim.x * CON_T;
  // pass 1: classified histogram
  for (int v = blockIdx.x * CON_T + (int)threadIdx.x; v < nv4; v += stride) {
    i4v d4 = aed4[v];
    i4v s4 = aes4[v];
#pragma unroll
    for (int j = 0; j < 4; ++j) {
      int b = (d4[j] - ASS0) >> BIN_SH;
      int si = s4[j] - ASS0;
      bool a0 = (sbm[si >> 5] >> (si & 31)) & 1u;
      atomicAdd(a0 ? &hA[b] : &hR[b], 1);
    }
  }
  if (blockIdx.x == 0) {
    for (int e = (nv4 << 2) + (int)threadIdx.x; e < E_a; e += CON_T) {
      int b = (aed[e] - ASS0) >> BIN_SH;
      int si = aes[e] - ASS0;
      bool a0 = (sbm[si >> 5] >> (si & 31)) & 1u;
      atomicAdd(a0 ? &hA[b] : &hR[b], 1);
    }
  }
  __syncthreads();
  // reserve: A0 fills up from b*cap, REST fills down from (b+1)*cap
  for (int b = threadIdx.x; b < NBINS; b += CON_T) {
    cA[b] = hA[b] ? atomicAdd(&cur0[b], hA[b]) : 0;
    cR[b] = hR[b] ? (atomicSub(&cur1[b], hR[b]) - hR[b]) : 0;
  }
  __syncthreads();
  // pass 2: scatter
  for (int v = blockIdx.x * CON_T + (int)threadIdx.x; v < nv4; v += stride) {
    i4v d4 = aed4[v];  // L2-hot from pass 1
    i4v s4 = aes4[v];
    f4v w4 = __builtin_nontemporal_load(&aw4[v]);
#pragma unroll
    for (int j = 0; j < 4; ++j) {
      int d = d4[j] - ASS0;
      int b = d >> BIN_SH;
      int si = s4[j] - ASS0;
      bool a0 = (sbm[si >> 5] >> (si & 31)) & 1u;
      u2v q;
      if (a0) {
        u2v lt = ltv[s4[j]];  // .y = tanh snapshot (kp ran before kc)
        q.x = (unsigned)(d & BIN_MK);
        q.y = __float_as_uint(__uint_as_float(lt.y) * w4[j]);
        csr[atomicAdd(&cA[b], 1)] = q;
      } else {
        q.x = ((unsigned)s4[j] << BIN_SH) | (unsigned)(d & BIN_MK);
        q.y = __float_as_uint(w4[j]);
        csr[atomicAdd(&cR[b], 1)] = q;
      }
    }
  }
  if (blockIdx.x == 0) {
    for (int e = (nv4 << 2) + (int)threadIdx.x; e < E_a; e += CON_T) {
      int d = aed[e] - ASS0;
      int b = d >> BIN_SH;
      int si = aes[e] - ASS0;
      bool a0 = (sbm[si >> 5] >> (si & 31)) & 1u;
      u2v q;
      if (a0) {
        u2v lt = ltv[aes[e]];
        q.x = (unsigned)(d & BIN_MK);
        q.y = __float_as_uint(__uint_as_float(lt.y) * aw[e]);
        csr[atomicAdd(&cA[b], 1)] = q;
      } else {
        q.x = ((unsigned)aes[e] << BIN_SH) | (unsigned)(d & BIN_MK);
        q.y = __float_as_uint(aw[e]);
        csr[atomicAdd(&cR[b], 1)] = q;
      }
    }
  }
}

// round 0: pure stream over A0 (contributions precomputed); one block/bin
__global__ __launch_bounds__(1024) void kRa(int* flags,
                                            const int* __restrict__ cur0,
                                            const u2v* __restrict__ csr,
                                            float* __restrict__ mem,
                                            u2v* __restrict__ ltv, int cap) {
  __shared__ float slice[BIN_SZ];
  __shared__ int smask[BIN_SZ];
  __shared__ int newfront;
  int tid = threadIdx.x;
  int bin = blockIdx.x;
  if (tid < BIN_SZ) {
    slice[tid] = 0.f;
    smask[tid] = 0;
  }
  if (tid == 0) newfront = 0;
  __syncthreads();
  int e0 = bin * cap;
  int e1 = cur0[bin];
  int e = e0 + tid;
  for (; e + 3 * 1024 < e1; e += 4 * 1024) {
    u2v q0 = __builtin_nontemporal_load(&csr[e]);
    u2v q1 = __builtin_nontemporal_load(&csr[e + 1024]);
    u2v q2 = __builtin_nontemporal_load(&csr[e + 2048]);
    u2v q3 = __builtin_nontemporal_load(&csr[e + 3072]);
    atomicAdd(&slice[q0.x], __uint_as_float(q0.y));
    smask[q0.x] = 1;
    atomicAdd(&slice[q1.x], __uint_as_float(q1.y));
    smask[q1.x] = 1;
    atomicAdd(&slice[q2.x], __uint_as_float(q2.y));
    smask[q2.x] = 1;
    atomicAdd(&slice[q3.x], __uint_as_float(q3.y));
    smask[q3.x] = 1;
  }
  for (; e < e1; e += 1024) {
    u2v q = __builtin_nontemporal_load(&csr[e]);
    atomicAdd(&slice[q.x], __uint_as_float(q.y));
    smask[q.x] = 1;
  }
  __syncthreads();
  if (tid < BIN_SZ) {
    int d = bin * BIN_SZ + tid;
    if (d < NDST && smask[tid]) {
      int node = ASS0 + d;
      float nv = mem[node] + slice[tid];
      u2v lt = ltv[node];
      if (lt.x == 255u) {  // first receipt -> fires at round 1
        u2v nl;
        nl.x = 1u;
        if (node < OUT0) {
          nl.y = __float_as_uint(tanhf(nv));
          ltv[node] = nl;
          mem[node] = 0.f;
          newfront = 1;
        } else {
          nl.y = 0u;
          ltv[node] = nl;
          mem[node] = nv;
        }
      } else {
        mem[node] = nv;  // level-0 node: fired this round, accumulates fresh
      }
    }
  }
  __syncthreads();
  if (tid == 0 && newfront) flags[1] = 1;
}

// round 1 edge pass over REST: grid NBINS*SPLIT x 256; collects survivors
__global__ __launch_bounds__(256) void kRe(int* flags,
                                           const int* __restrict__ cur1,
                                           const u2v* __restrict__ csr,
                                           const u2v* __restrict__ ltv,
                                           float* __restrict__ gslice,
                                           char* __restrict__ gmask,
                                           u2v* __restrict__ ssur, int* scur,
                                           int cap, int scap) {
  if (flags[1] == 0) return;
  __shared__ float slice[BIN_SZ];
  __shared__ int smask[BIN_SZ];
  int tid = threadIdx.x;
  int bin = blockIdx.x >> 3;  // SPLIT == 8
  int sub = blockIdx.x & (SPLIT - 1);
  for (int i = tid; i < BIN_SZ; i += 256) {
    slice[i] = 0.f;
    smask[i] = 0;
  }
  __syncthreads();
  int e0 = cur1[bin];
  int e1 = (bin + 1) * cap;
  int len = e1 - e0;
  int chunk = (len + SPLIT - 1) / SPLIT;
  int s0 = e0 + sub * chunk;
  int s1 = min(s0 + chunk, e1);
  for (int e = s0 + tid; e < s1; e += 256) {
    u2v q = __builtin_nontemporal_load(&csr[e]);
    u2v lt = ltv[q.x >> BIN_SH];
    if (lt.x == 1u) {
      atomicAdd(&slice[q.x & BIN_MK],
                __uint_as_float(lt.y) * __uint_as_float(q.y));
      smask[q.x & BIN_MK] = 1;
    } else if (lt.x == 255u) {
      // src still unreached: only these can fire at rounds >= 2
      int pos = atomicAdd(&scur[bin], 1);
      if (pos < bin * scap + scap)
        ssur[pos] = q;
      else
        flags[30] = 1;  // overflow: tail falls back to REST scan
    }
  }
  __syncthreads();
  int base = blockIdx.x * BIN_SZ;
  for (int i = tid; i < BIN_SZ; i += 256) {
    gslice[base + i] = slice[i];
    gmask[base + i] = (char)smask[i];
  }
}

// round 1 node pass: merge SPLIT partials + epilogue; grid NBINS x 512
__global__ __launch_bounds__(512) void kRn(int* flags,
                                           const float* __restrict__ gslice,
                                           const char* __restrict__ gmask,
                                           float* __restrict__ mem,
                                           u2v* __restrict__ ltv) {
  if (flags[1] == 0) return;
  __shared__ int newfront;
  int tid = threadIdx.x;
  int bin = blockIdx.x;
  if (tid == 0) newfront = 0;
  __syncthreads();
  float sv = 0.f;
  int mk = 0;
  int base = bin * SPLIT * BIN_SZ + tid;
#pragma unroll
  for (int s = 0; s < SPLIT; ++s) {
    sv += gslice[base + s * BIN_SZ];
    mk |= (int)gmask[base + s * BIN_SZ];
  }
  int d = bin * BIN_SZ + tid;
  if (d < NDST && mk) {
    int node = ASS0 + d;
    float nv = mem[node] + sv;
    u2v lt = ltv[node];
    if (lt.x == 255u) {
      u2v nl;
      nl.x = 2u;
      if (node < OUT0) {
        nl.y = __float_as_uint(tanhf(nv));
        ltv[node] = nl;
        mem[node] = 0.f;
        newfront = 1;
      } else {
        nl.y = 0u;
        ltv[node] = nl;
        mem[node] = nv;
      }
    } else {
      mem[node] = nv;
    }
  }
  __syncthreads();
  if (tid == 0 && newfront) flags[2] = 1;
}

// rounds 2..23 + output write, ONE cooperative kernel over survivors (or
// REST if the survivor buffer overflowed). Uniform early break when empty.
__global__ __launch_bounds__(1024) void kTail(int* flags,
                                              const int* __restrict__ cur1,
                                              const u2v* __restrict__ csr,
                                              const u2v* __restrict__ ssur,
                                              const int* __restrict__ scur,
                                              float* __restrict__ mem,
                                              u2v* __restrict__ ltv,
                                              float* __restrict__ out, int cap,
                                              int scap) {
  cg::grid_group g = cg::this_grid();
  __shared__ float slice[BIN_SZ];
  __shared__ int smask[BIN_SZ];
  __shared__ int newfront;
  int tid = threadIdx.x;
  int bin = blockIdx.x;
  bool useS = (flags[30] == 0);
  int e0 = useS ? bin * scap : cur1[bin];
  int e1 = useS ? min(scur[bin], bin * scap + scap) : (bin + 1) * cap;
  const u2v* E = useS ? ssur : csr;
  for (int r = 2; r < NUM_ROUNDS; ++r) {
    if (flags[r] == 0) break;  // uniform across grid
    if (tid < BIN_SZ) {
      slice[tid] = 0.f;
      smask[tid] = 0;
    }
    if (tid == 0) newfront = 0;
    __syncthreads();
    unsigned rl = (unsigned)r;
    for (int e = e0 + tid; e < e1; e += 1024) {
      u2v q = E[e];
      u2v lt = ltv[q.x >> BIN_SH];
      if (lt.x == rl) {
        atomicAdd(&slice[q.x & BIN_MK],
                  __uint_as_float(lt.y) * __uint_as_float(q.y));
        smask[q.x & BIN_MK] = 1;
      }
    }
    __syncthreads();
    if (tid < BIN_SZ) {
      int d = bin * BIN_SZ + tid;
      if (d < NDST && smask[tid]) {
        int node = ASS0 + d;
        float nv = mem[node] + slice[tid];
        u2v lt = ltv[node];
        if (lt.x == 255u) {
          u2v nl;
          nl.x = (unsigned)(r + 1);
          if (node < OUT0) {
            nl.y = __float_as_uint(tanhf(nv));
            ltv[node] = nl;
            mem[node] = 0.f;
            newfront = 1;
          } else {
            nl.y = 0u;
            ltv[node] = nl;
            mem[node] = nv;
          }
        } else {
          mem[node] = nv;
        }
      }
    }
    __syncthreads();
    if (tid == 0 && newfront) flags[r + 1] = 1;
    g.sync();
  }
  // output write (owning block wrote all mem for its dst range)
  if (tid < BIN_SZ) {
    int d = bin * BIN_SZ + tid;
    int node = ASS0 + d;
    if (d < NDST && node >= OUT0) out[node - OUT0] = tanhf(mem[node]);
  }
}

__global__ __launch_bounds__(256) void ko(const float* __restrict__ mem,
                                          float* __restrict__ out) {
  int i = blockIdx.x * 256 + threadIdx.x;
  if (i < OUT_F) out[i] = tanhf(mem[OUT0 + i]);
}

// ---------------------------------------------------------------------------
// Fallback dense multi-kernel path if ws too small.
// ---------------------------------------------------------------------------

__global__ __launch_bounds__(256) void k_init(float* mem, float* delta,
                                              int* status, int* got) {
  int i = blockIdx.x * 256 + threadIdx.x;
  if (i < TOTAL) {
    mem[i] = 0.f;
    delta[i] = 0.f;
    status[i] = 0;
    got[i] = 0;
  }
}
__global__ __launch_bounds__(256) void k_input(const float* __restrict__ x,
                                               const float* __restrict__ w,
                                               const int* __restrict__ src,
                                               const int* __restrict__ dst,
                                               int n, float* mem, int* got) {
  for (int e = blockIdx.x * 256 + threadIdx.x; e < n; e += gridDim.x * 256) {
    atomicAdd(&mem[dst[e]], x[src[e]] * w[e]);
    got[dst[e]] = 1;
  }
}
__global__ __launch_bounds__(256) void k_status0(int* status, int* got) {
  int i = blockIdx.x * 256 + threadIdx.x;
  if (i < TOTAL) {
    status[i] = got[i] ? 1 : 0;
    got[i] = 0;
  }
}
__global__ __launch_bounds__(256) void k_edge(const float* __restrict__ w,
                                              const int* __restrict__ src,
                                              const int* __restrict__ dst,
                                              int n,
                                              const float* __restrict__ mem,
                                              const int* __restrict__ status,
                                              float* delta, int* got) {
  for (int e = blockIdx.x * 256 + threadIdx.x; e < n; e += gridDim.x * 256) {
    int s = src[e];
    if (status[s] == 1) {
      atomicAdd(&delta[dst[e]], tanhf(mem[s]) * w[e]);
      got[dst[e]] = 1;
    }
  }
}
__global__ __launch_bounds__(256) void k_update(float* mem, float* delta,
                                                int* status, int* got) {
  int i = blockIdx.x * 256 + threadIdx.x;
  if (i < TOTAL) {
    int st = status[i];
    bool fire = (st == 1) && (i >= ASS0) && (i < OUT0);
    float d = delta[i];
    mem[i] = fire ? d : (mem[i] + d);
    status[i] = fire ? 2 : ((got[i] && st == 0) ? 1 : st);
    delta[i] = 0.f;
    got[i] = 0;
  }
}

extern "C" void kernel_launch(void* const* d_in, const int* in_sizes, int n_in,
                              void* d_out, int out_size, void* d_ws,
                              size_t ws_size, hipStream_t stream) {
  const float* x = (const float*)d_in[0];
  const float* iw = (const float*)d_in[1];
  const float* aw = (const float*)d_in[2];
  const int* ies = (const int*)d_in[3];
  const int* ied = (const int*)d_in[4];
  const int* aes = (const int*)d_in[5];
  const int* aed = (const int*)d_in[6];
  int E_in = in_sizes[1];
  int E_a = in_sizes[2];
  float* out = (float*)d_out;
  char* ws = (char*)d_ws;

  // fixed per-bin capacity: 1.3x mean, rounded to 256 (≈48 sigma margin)
  int cap = (((E_a / NBINS) * 13) / 10 + 255) & ~255;
  int scap = cap / 4;

  // layout: csr | ssur | ltv | mem | cur0 | cur1 | scur | flags | bm |
  //         gslice | gmask
  size_t off_csr = 0;
  size_t off_ssur = off_csr + (size_t)NBINS * cap * 8;
  size_t off_ltv = off_ssur + (size_t)NBINS * scap * 8;
  size_t off_mem = off_ltv + (size_t)TOTAL * 8;
  size_t off_cur0 = off_mem + (size_t)TOTAL * 4;
  size_t off_cur1 = off_cur0 + (size_t)NBINS * 4;
  size_t off_scur = off_cur1 + (size_t)NBINS * 4;
  size_t off_flags = off_scur + (size_t)NBINS * 4;
  size_t off_bm = off_flags + 32 * 4;
  size_t off_gsl = off_bm + (size_t)NBM32 * 4;
  size_t off_gmk = off_gsl + (size_t)NBINS * SPLIT * BIN_SZ * 4;
  size_t need = off_gmk + (size_t)NBINS * SPLIT * BIN_SZ;

  if (ws_size >= need) {
    u2v* csr = (u2v*)(ws + off_csr);
    u2v* ssur = (u2v*)(ws + off_ssur);
    u2v* ltv = (u2v*)(ws + off_ltv);
    float* mem = (float*)(ws + off_mem);
    int* cur0 = (int*)(ws + off_cur0);
    int* cur1 = (int*)(ws + off_cur1);
    int* scur = (int*)(ws + off_scur);
    int* flags = (int*)(ws + off_flags);
    unsigned* bm = (unsigned*)(ws + off_bm);
    float* gslice = (float*)(ws + off_gsl);
    char* gmask = ws + off_gmk;

    kz<<<(TOTAL + 255) / 256, 256, 0, stream>>>(mem, ltv, flags, cur0, cur1,
                                                scur, bm, cap, scap);
    ki<<<(E_in + 255) / 256, 256, 0, stream>>>(x, iw, ies, ied, E_in, mem,
                                               (unsigned int*)ltv, bm);
    kp<<<(ASS + 255) / 256, 256, 0, stream>>>(mem, ltv);
    kc<<<NCON, CON_T, 0, stream>>>(aes, aed, aw, E_a, cur0, cur1, ltv, bm,
                                   csr);
    kRa<<<NBINS, 1024, 0, stream>>>(flags, cur0, csr, mem, ltv, cap);
    kRe<<<NBINS * SPLIT, 256, 0, stream>>>(flags, cur1, csr, ltv, gslice,
                                           gmask, ssur, scur, cap, scap);
    kRn<<<NBINS, 512, 0, stream>>>(flags, gslice, gmask, mem, ltv);
    void* targs[] = {(void*)&flags, (void*)&cur1, (void*)&csr,  (void*)&ssur,
                     (void*)&scur,  (void*)&mem,  (void*)&ltv,  (void*)&out,
                     (void*)&cap,   (void*)&scap};
    hipLaunchCooperativeKernel((void*)kTail, dim3(NBINS), dim3(1024), targs, 0,
                               stream);
    return;
  }

  // fallback: dense path
  float* mem = (float*)ws;
  float* delta = mem + TOTAL;
  int* status = (int*)(delta + TOTAL);
  int* got = status + TOTAL;
  const int nodeBlocks = (TOTAL + 255) / 256;
  k_init<<<nodeBlocks, 256, 0, stream>>>(mem, delta, status, got);
  int inBlocks = (E_in + 255) / 256;
  if (inBlocks > 1024) inBlocks = 1024;
  k_input<<<inBlocks, 256, 0, stream>>>(x, iw, ies, ied, E_in, mem, got);
  k_status0<<<nodeBlocks, 256, 0, stream>>>(status, got);
  int eBlocks = (E_a + 255) / 256;
  if (eBlocks > 2048) eBlocks = 2048;
  for (int r = 0; r < NUM_ROUNDS; ++r) {
    k_edge<<<eBlocks, 256, 0, stream>>>(aw, aes, aed, E_a, mem, status, delta,
                                        got);
    k_update<<<nodeBlocks, 256, 0, stream>>>(mem, delta, status, got);
  }
  ko<<<(OUT_F + 255) / 256, 256, 0, stream>>>(mem, out);
}

// Round 16
// 159.351 us; speedup vs baseline: 1.0523x; 1.0523x over previous
//
#include <hip/hip_runtime.h>
#include <hip/hip_cooperative_groups.h>

namespace cg = cooperative_groups;

#define IN_F 1024
#define ASS 100000
#define OUT_F 1024
#define TOTAL (IN_F + ASS + OUT_F)  // 102048
#define ASS0 IN_F
#define OUT0 (IN_F + ASS)
#define NDST (ASS + OUT_F)  // 101024 destinations, node = ASS0 + d
#define NUM_ROUNDS 24

#define BIN_SZ 512  // dst nodes per bin
#define BIN_SH 9
#define BIN_MK 511
#define NBINS ((NDST + BIN_SZ - 1) / BIN_SZ)  // 198
#define NCON 512    // construction blocks
#define CON_T 1024  // construction threads per block
#define SPLIT 8     // sub-blocks per bin in rounds 0,1
#define NBM32 3136  // level-0 bitmask words (>= ASS/32)

typedef int i4v __attribute__((ext_vector_type(4)));
typedef float f4v __attribute__((ext_vector_type(4)));
typedef unsigned int u2v __attribute__((ext_vector_type(2)));

// ---------------------------------------------------------------------------
// Each assoc neuron fires exactly once at BFS level L(u).
// csr[e] = {src<<9 | dstoff, w} packed 8B in fixed-capacity per-bin regions;
// kc = round-14 form EXACTLY (histogram on aed only -> reserve -> scatter,
// no gathers, no classification: r15's split kc doubled segments and
// gather-thrashed L2 -> WRITE 58->123MB. Reverted).
// Level-0 bitmask bm (12.5KB, built by ki) is used in kRe's LDS instead:
//   r0: only level-0-src edges can fire -> !a0 edges skipped, NO gather;
//       a0 edges gather ltv just for tv.
//   r1: a0 edges can be neither active (lev0) nor survivors -> skip 40%
//       of gathers; others: active if lev==1, survivor-append if lev==255.
// Rounds 0,1: kRe (NBINS*8 x 256, LDS partial slices) + kRn (merge+epilogue).
// Rounds 2..23 + output write: ONE cooperative kTail over survivors
// (uniform early break; overflow flags[30] -> full-bin fallback).
// Torn-8B-read safety: ltv writes only transition lev 255->r+1, so a reader
// checking lev==r can never pair a stale tv with a matching lev.
// ---------------------------------------------------------------------------

__global__ __launch_bounds__(256) void kz(float* mem, u2v* ltv, int* flags,
                                          int* bin_cursor, int* scur,
                                          unsigned* bm, int cap, int scap) {
  int i = blockIdx.x * 256 + threadIdx.x;
  int gs = gridDim.x * 256;
  u2v init;
  init.x = 255u;
  init.y = 0u;
  for (int k = i; k < TOTAL; k += gs) {
    mem[k] = 0.f;
    ltv[k] = init;
  }
  for (int k = i; k < NBINS; k += gs) {
    bin_cursor[k] = k * cap;
    scur[k] = k * scap;
  }
  for (int k = i; k < NBM32; k += gs) bm[k] = 0u;
  if (i < 32) flags[i] = 0;
}

__global__ __launch_bounds__(256) void ki(const float* __restrict__ x,
                                          const float* __restrict__ iw,
                                          const int* __restrict__ ies,
                                          const int* __restrict__ ied, int E_in,
                                          float* mem, unsigned int* ltv_raw,
                                          unsigned* bm) {
  int e = blockIdx.x * 256 + threadIdx.x;
  if (e < E_in) {
    int d = ied[e];  // always an assoc node by construction
    atomicAdd(&mem[d], x[ies[e]] * iw[e]);
    ltv_raw[2 * d] = 0u;  // lev = 0; benign race, all writers store 0
    int b = d - ASS0;
    atomicOr(&bm[b >> 5], 1u << (b & 31));
  }
}

// snapshot level-0 frontier: tv = tanh(mem), mem = 0
__global__ __launch_bounds__(256) void kp(float* mem, u2v* ltv) {
  int i = blockIdx.x * 256 + threadIdx.x;
  if (i < ASS) {
    int node = ASS0 + i;
    u2v lt = ltv[node];
    if (lt.x == 0u) {
      lt.y = __float_as_uint(tanhf(mem[node]));
      ltv[node] = lt;
      mem[node] = 0.f;
    }
  }
}

// construction (round-14 form): histogram chunk -> reserve -> scatter.
// aed read twice (2nd pass L2-hot); aes/aw streamed NT once. No gathers.
__global__ __launch_bounds__(CON_T) void kc(const int* __restrict__ aes,
                                            const int* __restrict__ aed,
                                            const float* __restrict__ aw,
                                            int E_a, int* bin_cursor,
                                            u2v* __restrict__ csr) {
  __shared__ int h[2][NBINS];
  __shared__ int cur[NBINS];
  for (int b = threadIdx.x; b < 2 * NBINS; b += CON_T)
    h[b >= NBINS][b >= NBINS ? b - NBINS : b] = 0;
  __syncthreads();
  int cp = (threadIdx.x >> 6) & 1;
  const i4v* aed4 = (const i4v*)aed;
  const i4v* aes4 = (const i4v*)aes;
  const f4v* aw4 = (const f4v*)aw;
  int nv4 = E_a >> 2;
  int stride = gridDim.x * CON_T;
  // pass 1: local histogram (aed only)
  for (int v = blockIdx.x * CON_T + (int)threadIdx.x; v < nv4; v += stride) {
    i4v d4 = aed4[v];
    atomicAdd(&h[cp][(d4.x - ASS0) >> BIN_SH], 1);
    atomicAdd(&h[cp][(d4.y - ASS0) >> BIN_SH], 1);
    atomicAdd(&h[cp][(d4.z - ASS0) >> BIN_SH], 1);
    atomicAdd(&h[cp][(d4.w - ASS0) >> BIN_SH], 1);
  }
  if (blockIdx.x == 0) {
    for (int e = (nv4 << 2) + (int)threadIdx.x; e < E_a; e += CON_T)
      atomicAdd(&h[cp][(aed[e] - ASS0) >> BIN_SH], 1);
  }
  __syncthreads();
  // reserve
  for (int b = threadIdx.x; b < NBINS; b += CON_T) {
    int c = h[0][b] + h[1][b];
    cur[b] = c ? atomicAdd(&bin_cursor[b], c) : 0;
  }
  __syncthreads();
  // pass 2: scatter
  for (int v = blockIdx.x * CON_T + (int)threadIdx.x; v < nv4; v += stride) {
    i4v d4 = aed4[v];  // L2-hot from pass 1
    i4v s4 = __builtin_nontemporal_load(&aes4[v]);
    f4v w4 = __builtin_nontemporal_load(&aw4[v]);
#pragma unroll
    for (int j = 0; j < 4; ++j) {
      int d = d4[j] - ASS0;
      int pos = atomicAdd(&cur[d >> BIN_SH], 1);
      u2v q;
      q.x = ((unsigned)s4[j] << BIN_SH) | (unsigned)(d & BIN_MK);
      q.y = __float_as_uint(w4[j]);
      csr[pos] = q;
    }
  }
  if (blockIdx.x == 0) {
    for (int e = (nv4 << 2) + (int)threadIdx.x; e < E_a; e += CON_T) {
      int d = aed[e] - ASS0;
      int pos = atomicAdd(&cur[d >> BIN_SH], 1);
      u2v q;
      q.x = ((unsigned)aes[e] << BIN_SH) | (unsigned)(d & BIN_MK);
      q.y = __float_as_uint(aw[e]);
      csr[pos] = q;
    }
  }
}

// rounds 0,1 edge pass: grid NBINS*SPLIT x 256; level-0 bitmask in LDS
// r0: only a0 edges active (no lev check, gather tv only for them)
// r1: a0 edges skipped entirely; others active(lev==1)/survivor(lev==255)
__global__ __launch_bounds__(256) void kRe(int r, int collect, int* flags,
                                           const int* __restrict__ bin_cursor,
                                           const u2v* __restrict__ csr,
                                           const u2v* __restrict__ ltv,
                                           const unsigned* __restrict__ bm,
                                           float* __restrict__ gslice,
                                           char* __restrict__ gmask,
                                           u2v* __restrict__ ssur, int* scur,
                                           int cap, int scap) {
  if (r > 0 && flags[r] == 0) return;
  __shared__ unsigned sbm[NBM32];
  __shared__ float slice[BIN_SZ];
  __shared__ int smask[BIN_SZ];
  int tid = threadIdx.x;
  for (int k = tid; k < NBM32; k += 256) sbm[k] = bm[k];
  for (int i = tid; i < BIN_SZ; i += 256) {
    slice[i] = 0.f;
    smask[i] = 0;
  }
  __syncthreads();
  int bin = blockIdx.x >> 3;  // SPLIT == 8
  int sub = blockIdx.x & (SPLIT - 1);
  int e0 = bin * cap;
  int e1 = bin_cursor[bin];
  int len = e1 - e0;
  int chunk = (len + SPLIT - 1) / SPLIT;
  int s0 = e0 + sub * chunk;
  int s1 = min(s0 + chunk, e1);
  unsigned rl = (unsigned)r;
#pragma unroll 4
  for (int e = s0 + tid; e < s1; e += 256) {
    u2v q = __builtin_nontemporal_load(&csr[e]);
    int si = (int)(q.x >> BIN_SH) - ASS0;  // assoc-edge srcs are assoc nodes
    bool a0 = (sbm[si >> 5] >> (si & 31)) & 1u;
    if (r == 0) {
      if (a0) {  // lev==0==r guaranteed; gather only for tv
        u2v lt = ltv[q.x >> BIN_SH];
        atomicAdd(&slice[q.x & BIN_MK],
                  __uint_as_float(lt.y) * __uint_as_float(q.y));
        smask[q.x & BIN_MK] = 1;
      }
    } else if (!a0) {  // a0 srcs (lev 0) can't be active or survivors at r>=1
      u2v lt = ltv[q.x >> BIN_SH];
      if (lt.x == rl) {
        atomicAdd(&slice[q.x & BIN_MK],
                  __uint_as_float(lt.y) * __uint_as_float(q.y));
        smask[q.x & BIN_MK] = 1;
      } else if (collect && lt.x == 255u) {
        // src still unreached: only these can fire at rounds >= 2
        int pos = atomicAdd(&scur[bin], 1);
        if (pos < bin * scap + scap)
          ssur[pos] = q;
        else
          flags[30] = 1;  // overflow: tail falls back to full-bin scan
      }
    }
  }
  __syncthreads();
  int base = blockIdx.x * BIN_SZ;
  for (int i = tid; i < BIN_SZ; i += 256) {
    gslice[base + i] = slice[i];
    gmask[base + i] = (char)smask[i];
  }
}

// rounds 0,1 node pass: merge SPLIT partials + epilogue; grid NBINS x 512
__global__ __launch_bounds__(512) void kRn(int r, int* flags,
                                           const float* __restrict__ gslice,
                                           const char* __restrict__ gmask,
                                           float* __restrict__ mem,
                                           u2v* __restrict__ ltv) {
  if (r > 0 && flags[r] == 0) return;
  __shared__ int newfront;
  int tid = threadIdx.x;
  int bin = blockIdx.x;
  if (tid == 0) newfront = 0;
  __syncthreads();
  float sv = 0.f;
  int mk = 0;
  int base = bin * SPLIT * BIN_SZ + tid;
#pragma unroll
  for (int s = 0; s < SPLIT; ++s) {
    sv += gslice[base + s * BIN_SZ];
    mk |= (int)gmask[base + s * BIN_SZ];
  }
  int d = bin * BIN_SZ + tid;
  if (d < NDST && mk) {
    int node = ASS0 + d;
    float nv = mem[node] + sv;
    u2v lt = ltv[node];  // only this block ever writes this node's ltv
    if (lt.x == 255u) {  // first receipt: becomes working, fires next round
      u2v nl;
      nl.x = (unsigned)(r + 1);
      if (node < OUT0) {
        nl.y = __float_as_uint(tanhf(nv));  // snapshot at fire time
        ltv[node] = nl;
        mem[node] = 0.f;  // fired neurons erase memory
        newfront = 1;     // benign LDS race
      } else {
        nl.y = 0u;
        ltv[node] = nl;
        mem[node] = nv;  // outputs never fire, just accumulate
      }
    } else {
      mem[node] = nv;
    }
  }
  __syncthreads();
  if (tid == 0 && newfront) flags[r + 1] = 1;
}

// rounds 2..23 + output write, ONE cooperative kernel over survivors (or
// full bin regions if the survivor buffer overflowed). Uniform early break.
__global__ __launch_bounds__(1024) void kTail(
    int* flags, const int* __restrict__ bin_cursor,
    const u2v* __restrict__ csr, const u2v* __restrict__ ssur,
    const int* __restrict__ scur, float* __restrict__ mem,
    u2v* __restrict__ ltv, float* __restrict__ out, int cap, int scap) {
  cg::grid_group g = cg::this_grid();
  __shared__ float slice[BIN_SZ];
  __shared__ int smask[BIN_SZ];
  __shared__ int newfront;
  int tid = threadIdx.x;
  int bin = blockIdx.x;
  bool useS = (flags[30] == 0);
  int e0 = useS ? bin * scap : bin * cap;
  int e1 = useS ? min(scur[bin], bin * scap + scap) : bin_cursor[bin];
  const u2v* E = useS ? ssur : csr;
  for (int r = 2; r < NUM_ROUNDS; ++r) {
    if (flags[r] == 0) break;  // uniform across grid
    if (tid < BIN_SZ) {
      slice[tid] = 0.f;
      smask[tid] = 0;
    }
    if (tid == 0) newfront = 0;
    __syncthreads();
    unsigned rl = (unsigned)r;
    for (int e = e0 + tid; e < e1; e += 1024) {
      u2v q = E[e];
      u2v lt = ltv[q.x >> BIN_SH];
      if (lt.x == rl) {
        atomicAdd(&slice[q.x & BIN_MK],
                  __uint_as_float(lt.y) * __uint_as_float(q.y));
        smask[q.x & BIN_MK] = 1;
      }
    }
    __syncthreads();
    if (tid < BIN_SZ) {
      int d = bin * BIN_SZ + tid;
      if (d < NDST && smask[tid]) {
        int node = ASS0 + d;
        float nv = mem[node] + slice[tid];
        u2v lt = ltv[node];
        if (lt.x == 255u) {
          u2v nl;
          nl.x = (unsigned)(r + 1);
          if (node < OUT0) {
            nl.y = __float_as_uint(tanhf(nv));
            ltv[node] = nl;
            mem[node] = 0.f;
            newfront = 1;
          } else {
            nl.y = 0u;
            ltv[node] = nl;
            mem[node] = nv;
          }
        } else {
          mem[node] = nv;
        }
      }
    }
    __syncthreads();
    if (tid == 0 && newfront) flags[r + 1] = 1;
    g.sync();
  }
  // output write (owning block wrote all mem for its dst range)
  if (tid < BIN_SZ) {
    int d = bin * BIN_SZ + tid;
    int node = ASS0 + d;
    if (d < NDST && node >= OUT0) out[node - OUT0] = tanhf(mem[node]);
  }
}

__global__ __launch_bounds__(256) void ko(const float* __restrict__ mem,
                                          float* __restrict__ out) {
  int i = blockIdx.x * 256 + threadIdx.x;
  if (i < OUT_F) out[i] = tanhf(mem[OUT0 + i]);
}

// ---------------------------------------------------------------------------
// Fallback dense multi-kernel path if ws too small.
// ---------------------------------------------------------------------------

__global__ __launch_bounds__(256) void k_init(float* mem, float* delta,
                                              int* status, int* got) {
  int i = blockIdx.x * 256 + threadIdx.x;
  if (i < TOTAL) {
    mem[i] = 0.f;
    delta[i] = 0.f;
    status[i] = 0;
    got[i] = 0;
  }
}
__global__ __launch_bounds__(256) void k_input(const float* __restrict__ x,
                                               const float* __restrict__ w,
                                               const int* __restrict__ src,
                                               const int* __restrict__ dst,
                                               int n, float* mem, int* got) {
  for (int e = blockIdx.x * 256 + threadIdx.x; e < n; e += gridDim.x * 256) {
    atomicAdd(&mem[dst[e]], x[src[e]] * w[e]);
    got[dst[e]] = 1;
  }
}
__global__ __launch_bounds__(256) void k_status0(int* status, int* got) {
  int i = blockIdx.x * 256 + threadIdx.x;
  if (i < TOTAL) {
    status[i] = got[i] ? 1 : 0;
    got[i] = 0;
  }
}
__global__ __launch_bounds__(256) void k_edge(const float* __restrict__ w,
                                              const int* __restrict__ src,
                                              const int* __restrict__ dst,
                                              int n,
                                              const float* __restrict__ mem,
                                              const int* __restrict__ status,
                                              float* delta, int* got) {
  for (int e = blockIdx.x * 256 + threadIdx.x; e < n; e += gridDim.x * 256) {
    int s = src[e];
    if (status[s] == 1) {
      atomicAdd(&delta[dst[e]], tanhf(mem[s]) * w[e]);
      got[dst[e]] = 1;
    }
  }
}
__global__ __launch_bounds__(256) void k_update(float* mem, float* delta,
                                                int* status, int* got) {
  int i = blockIdx.x * 256 + threadIdx.x;
  if (i < TOTAL) {
    int st = status[i];
    bool fire = (st == 1) && (i >= ASS0) && (i < OUT0);
    float d = delta[i];
    mem[i] = fire ? d : (mem[i] + d);
    status[i] = fire ? 2 : ((got[i] && st == 0) ? 1 : st);
    delta[i] = 0.f;
    got[i] = 0;
  }
}

extern "C" void kernel_launch(void* const* d_in, const int* in_sizes, int n_in,
                              void* d_out, int out_size, void* d_ws,
                              size_t ws_size, hipStream_t stream) {
  const float* x = (const float*)d_in[0];
  const float* iw = (const float*)d_in[1];
  const float* aw = (const float*)d_in[2];
  const int* ies = (const int*)d_in[3];
  const int* ied = (const int*)d_in[4];
  const int* aes = (const int*)d_in[5];
  const int* aed = (const int*)d_in[6];
  int E_in = in_sizes[1];
  int E_a = in_sizes[2];
  float* out = (float*)d_out;
  char* ws = (char*)d_ws;

  // fixed per-bin capacity: 1.3x mean, rounded to 256 (≈48 sigma margin)
  int cap = (((E_a / NBINS) * 13) / 10 + 255) & ~255;
  int scap = cap / 4;

  // layout: csr | ssur | ltv | mem | bin_cursor | scur | flags | bm |
  //         gslice | gmask
  size_t off_csr = 0;
  size_t off_ssur = off_csr + (size_t)NBINS * cap * 8;
  size_t off_ltv = off_ssur + (size_t)NBINS * scap * 8;
  size_t off_mem = off_ltv + (size_t)TOTAL * 8;
  size_t off_bcur = off_mem + (size_t)TOTAL * 4;
  size_t off_scur = off_bcur + (size_t)NBINS * 4;
  size_t off_flags = off_scur + (size_t)NBINS * 4;
  size_t off_bm = off_flags + 32 * 4;
  size_t off_gsl = off_bm + (size_t)NBM32 * 4;
  size_t off_gmk = off_gsl + (size_t)NBINS * SPLIT * BIN_SZ * 4;
  size_t need = off_gmk + (size_t)NBINS * SPLIT * BIN_SZ;

  if (ws_size >= need) {
    u2v* csr = (u2v*)(ws + off_csr);
    u2v* ssur = (u2v*)(ws + off_ssur);
    u2v* ltv = (u2v*)(ws + off_ltv);
    float* mem = (float*)(ws + off_mem);
    int* bin_cursor = (int*)(ws + off_bcur);
    int* scur = (int*)(ws + off_scur);
    int* flags = (int*)(ws + off_flags);
    unsigned* bm = (unsigned*)(ws + off_bm);
    float* gslice = (float*)(ws + off_gsl);
    char* gmask = ws + off_gmk;

    kz<<<(TOTAL + 255) / 256, 256, 0, stream>>>(mem, ltv, flags, bin_cursor,
                                                scur, bm, cap, scap);
    ki<<<(E_in + 255) / 256, 256, 0, stream>>>(x, iw, ies, ied, E_in, mem,
                                               (unsigned int*)ltv, bm);
    kp<<<(ASS + 255) / 256, 256, 0, stream>>>(mem, ltv);
    kc<<<NCON, CON_T, 0, stream>>>(aes, aed, aw, E_a, bin_cursor, csr);

    for (int r = 0; r < 2; ++r) {
      kRe<<<NBINS * SPLIT, 256, 0, stream>>>(r, r == 1 ? 1 : 0, flags,
                                             bin_cursor, csr, ltv, bm, gslice,
                                             gmask, ssur, scur, cap, scap);
      kRn<<<NBINS, 512, 0, stream>>>(r, flags, gslice, gmask, mem, ltv);
    }
    void* targs[] = {(void*)&flags, (void*)&bin_cursor, (void*)&csr,
                     (void*)&ssur,  (void*)&scur,       (void*)&mem,
                     (void*)&ltv,   (void*)&out,        (void*)&cap,
                     (void*)&scap};
    hipLaunchCooperativeKernel((void*)kTail, dim3(NBINS), dim3(1024), targs, 0,
                               stream);
    return;
  }

  // fallback: dense path
  float* mem = (float*)ws;
  float* delta = mem + TOTAL;
  int* status = (int*)(delta + TOTAL);
  int* got = status + TOTAL;
  const int nodeBlocks = (TOTAL + 255) / 256;
  k_init<<<nodeBlocks, 256, 0, stream>>>(mem, delta, status, got);
  int inBlocks = (E_in + 255) / 256;
  if (inBlocks > 1024) inBlocks = 1024;
  k_input<<<inBlocks, 256, 0, stream>>>(x, iw, ies, ied, E_in, mem, got);
  k_status0<<<nodeBlocks, 256, 0, stream>>>(status, got);
  int eBlocks = (E_a + 255) / 256;
  if (eBlocks > 2048) eBlocks = 2048;
  for (int r = 0; r < NUM_ROUNDS; ++r) {
    k_edge<<<eBlocks, 256, 0, stream>>>(aw, aes, aed, E_a, mem, status, delta,
                                        got);
    k_update<<<nodeBlocks, 256, 0, stream>>>(mem, delta, status, got);
  }
  ko<<<(OUT_F + 255) / 256, 256, 0, stream>>>(mem, out);
}

// Round 17
// 151.398 us; speedup vs baseline: 1.1076x; 1.0525x over previous
//
#include <hip/hip_runtime.h>
#include <hip/hip_cooperative_groups.h>

namespace cg = cooperative_groups;

#define IN_F 1024
#define ASS 100000
#define OUT_F 1024
#define TOTAL (IN_F + ASS + OUT_F)  // 102048
#define ASS0 IN_F
#define OUT0 (IN_F + ASS)
#define NDST (ASS + OUT_F)  // 101024 destinations, node = ASS0 + d
#define NUM_ROUNDS 24

#define BIN_SZ 512  // dst nodes per bin
#define BIN_SH 9
#define BIN_MK 511
#define NBINS ((NDST + BIN_SZ - 1) / BIN_SZ)  // 198
#define NCON 512    // construction blocks
#define CON_T 1024  // construction threads per block
#define SPLIT 8     // sub-blocks per bin in rounds 0,1
#define NBM32 3136  // level-0 bitmask words (>= ASS/32)
#define A0FLAG 0x80000000u

typedef int i4v __attribute__((ext_vector_type(4)));
typedef float f4v __attribute__((ext_vector_type(4)));
typedef unsigned int u2v __attribute__((ext_vector_type(2)));

// ---------------------------------------------------------------------------
// Each assoc neuron fires exactly once at BFS level L(u).
// csr[e] = {flag31 | src<<9 | dstoff, w} packed 8B in fixed-cap per-bin
// regions. flag31 = "src is level-0" (known pre-construction): kc computes it
// from a 12.5KB LDS bitmask while aes is already in registers -- kRe then
// tests a register bit instead of loading the bitmask per block.
//   r0: only flagged edges can fire (lev==0 guaranteed, no lev check);
//       gather ltv only for them (just for tv).
//   r1: flagged edges skipped entirely (can't be active or survivors).
// kc processes CONTIGUOUS per-block chunks so pass-2 re-reads its own slice
// L2-hot (grid-stride interleave defeated reuse: 62MB streams > 32MB L2).
// Rounds 0,1: kRe (NBINS*8 x 256, LDS partial slices) + kRn (merge+epilogue).
// Rounds 2..23 + output write: ONE cooperative kTail over survivors
// (uniform early break; overflow flags[30] -> full-bin fallback with masked
// src). Torn-8B-read safety: ltv writes only transition lev 255->r+1.
// ---------------------------------------------------------------------------

__global__ __launch_bounds__(256) void kz(float* mem, u2v* ltv, int* flags,
                                          int* bin_cursor, int* scur,
                                          unsigned* bm, int cap, int scap) {
  int i = blockIdx.x * 256 + threadIdx.x;
  int gs = gridDim.x * 256;
  u2v init;
  init.x = 255u;
  init.y = 0u;
  for (int k = i; k < TOTAL; k += gs) {
    mem[k] = 0.f;
    ltv[k] = init;
  }
  for (int k = i; k < NBINS; k += gs) {
    bin_cursor[k] = k * cap;
    scur[k] = k * scap;
  }
  for (int k = i; k < NBM32; k += gs) bm[k] = 0u;
  if (i < 32) flags[i] = 0;
}

__global__ __launch_bounds__(256) void ki(const float* __restrict__ x,
                                          const float* __restrict__ iw,
                                          const int* __restrict__ ies,
                                          const int* __restrict__ ied, int E_in,
                                          float* mem, unsigned int* ltv_raw,
                                          unsigned* bm) {
  int e = blockIdx.x * 256 + threadIdx.x;
  if (e < E_in) {
    int d = ied[e];  // always an assoc node by construction
    atomicAdd(&mem[d], x[ies[e]] * iw[e]);
    ltv_raw[2 * d] = 0u;  // lev = 0; benign race, all writers store 0
    int b = d - ASS0;
    atomicOr(&bm[b >> 5], 1u << (b & 31));
  }
}

// snapshot level-0 frontier: tv = tanh(mem), mem = 0
__global__ __launch_bounds__(256) void kp(float* mem, u2v* ltv) {
  int i = blockIdx.x * 256 + threadIdx.x;
  if (i < ASS) {
    int node = ASS0 + i;
    u2v lt = ltv[node];
    if (lt.x == 0u) {
      lt.y = __float_as_uint(tanhf(mem[node]));
      ltv[node] = lt;
      mem[node] = 0.f;
    }
  }
}

// construction: contiguous chunk histogram -> reserve -> scatter (+A0 flag).
// Pass 2 re-reads only this block's aed slice (L2-hot). No gathers.
__global__ __launch_bounds__(CON_T) void kc(const int* __restrict__ aes,
                                            const int* __restrict__ aed,
                                            const float* __restrict__ aw,
                                            int E_a, int* bin_cursor,
                                            const unsigned* __restrict__ bm,
                                            u2v* __restrict__ csr) {
  __shared__ unsigned sbm[NBM32];
  __shared__ int h[4][NBINS];
  __shared__ int cur[NBINS];
  for (int k = threadIdx.x; k < NBM32; k += CON_T) sbm[k] = bm[k];
  for (int b = threadIdx.x; b < 4 * NBINS; b += CON_T) h[b / NBINS][b % NBINS] = 0;
  __syncthreads();
  int cp = (threadIdx.x >> 6) & 3;
  const i4v* aed4 = (const i4v*)aed;
  const i4v* aes4 = (const i4v*)aes;
  const f4v* aw4 = (const f4v*)aw;
  int nv4 = E_a >> 2;
  int chunk4 = (nv4 + NCON - 1) / NCON;
  int v0 = blockIdx.x * chunk4;
  int v1 = min(v0 + chunk4, nv4);
  // pass 1: local histogram over contiguous chunk (aed only)
  for (int v = v0 + (int)threadIdx.x; v < v1; v += CON_T) {
    i4v d4 = aed4[v];
    atomicAdd(&h[cp][(d4.x - ASS0) >> BIN_SH], 1);
    atomicAdd(&h[cp][(d4.y - ASS0) >> BIN_SH], 1);
    atomicAdd(&h[cp][(d4.z - ASS0) >> BIN_SH], 1);
    atomicAdd(&h[cp][(d4.w - ASS0) >> BIN_SH], 1);
  }
  if (blockIdx.x == 0) {
    for (int e = (nv4 << 2) + (int)threadIdx.x; e < E_a; e += CON_T)
      atomicAdd(&h[cp][(aed[e] - ASS0) >> BIN_SH], 1);
  }
  __syncthreads();
  // reserve
  for (int b = threadIdx.x; b < NBINS; b += CON_T) {
    int c = h[0][b] + h[1][b] + h[2][b] + h[3][b];
    cur[b] = c ? atomicAdd(&bin_cursor[b], c) : 0;
  }
  __syncthreads();
  // pass 2: scatter (aed L2-hot; flag A0 via LDS bitmask)
  for (int v = v0 + (int)threadIdx.x; v < v1; v += CON_T) {
    i4v d4 = aed4[v];
    i4v s4 = __builtin_nontemporal_load(&aes4[v]);
    f4v w4 = __builtin_nontemporal_load(&aw4[v]);
#pragma unroll
    for (int j = 0; j < 4; ++j) {
      int d = d4[j] - ASS0;
      int si = s4[j] - ASS0;
      unsigned fl = ((sbm[si >> 5] >> (si & 31)) & 1u) ? A0FLAG : 0u;
      int pos = atomicAdd(&cur[d >> BIN_SH], 1);
      u2v q;
      q.x = fl | ((unsigned)s4[j] << BIN_SH) | (unsigned)(d & BIN_MK);
      q.y = __float_as_uint(w4[j]);
      csr[pos] = q;
    }
  }
  if (blockIdx.x == 0) {
    for (int e = (nv4 << 2) + (int)threadIdx.x; e < E_a; e += CON_T) {
      int d = aed[e] - ASS0;
      int si = aes[e] - ASS0;
      unsigned fl = ((sbm[si >> 5] >> (si & 31)) & 1u) ? A0FLAG : 0u;
      int pos = atomicAdd(&cur[d >> BIN_SH], 1);
      u2v q;
      q.x = fl | ((unsigned)aes[e] << BIN_SH) | (unsigned)(d & BIN_MK);
      q.y = __float_as_uint(aw[e]);
      csr[pos] = q;
    }
  }
}

// rounds 0,1 edge pass: grid NBINS*SPLIT x 256; A0 flag in bit 31
__global__ __launch_bounds__(256) void kRe(int r, int collect, int* flags,
                                           const int* __restrict__ bin_cursor,
                                           const u2v* __restrict__ csr,
                                           const u2v* __restrict__ ltv,
                                           float* __restrict__ gslice,
                                           char* __restrict__ gmask,
                                           u2v* __restrict__ ssur, int* scur,
                                           int cap, int scap) {
  if (r > 0 && flags[r] == 0) return;
  __shared__ float slice[BIN_SZ];
  __shared__ int smask[BIN_SZ];
  int tid = threadIdx.x;
  for (int i = tid; i < BIN_SZ; i += 256) {
    slice[i] = 0.f;
    smask[i] = 0;
  }
  __syncthreads();
  int bin = blockIdx.x >> 3;  // SPLIT == 8
  int sub = blockIdx.x & (SPLIT - 1);
  int e0 = bin * cap;
  int e1 = bin_cursor[bin];
  int len = e1 - e0;
  int chunk = (len + SPLIT - 1) / SPLIT;
  int s0 = e0 + sub * chunk;
  int s1 = min(s0 + chunk, e1);
  unsigned rl = (unsigned)r;
#pragma unroll 4
  for (int e = s0 + tid; e < s1; e += 256) {
    u2v q = __builtin_nontemporal_load(&csr[e]);
    if (r == 0) {
      if (q.x & A0FLAG) {  // level-0 src: lev==0==r guaranteed
        u2v lt = ltv[(q.x & ~A0FLAG) >> BIN_SH];
        atomicAdd(&slice[q.x & BIN_MK],
                  __uint_as_float(lt.y) * __uint_as_float(q.y));
        smask[q.x & BIN_MK] = 1;
      }
    } else if (!(q.x & A0FLAG)) {  // a0 can't be active or survivor at r>=1
      u2v lt = ltv[q.x >> BIN_SH];
      if (lt.x == rl) {
        atomicAdd(&slice[q.x & BIN_MK],
                  __uint_as_float(lt.y) * __uint_as_float(q.y));
        smask[q.x & BIN_MK] = 1;
      } else if (collect && lt.x == 255u) {
        // src still unreached: only these can fire at rounds >= 2
        int pos = atomicAdd(&scur[bin], 1);
        if (pos < bin * scap + scap)
          ssur[pos] = q;
        else
          flags[30] = 1;  // overflow: tail falls back to full-bin scan
      }
    }
  }
  __syncthreads();
  int base = blockIdx.x * BIN_SZ;
  for (int i = tid; i < BIN_SZ; i += 256) {
    gslice[base + i] = slice[i];
    gmask[base + i] = (char)smask[i];
  }
}

// rounds 0,1 node pass: merge SPLIT partials + epilogue; grid NBINS x 512
__global__ __launch_bounds__(512) void kRn(int r, int* flags,
                                           const float* __restrict__ gslice,
                                           const char* __restrict__ gmask,
                                           float* __restrict__ mem,
                                           u2v* __restrict__ ltv) {
  if (r > 0 && flags[r] == 0) return;
  __shared__ int newfront;
  int tid = threadIdx.x;
  int bin = blockIdx.x;
  if (tid == 0) newfront = 0;
  __syncthreads();
  float sv = 0.f;
  int mk = 0;
  int base = bin * SPLIT * BIN_SZ + tid;
#pragma unroll
  for (int s = 0; s < SPLIT; ++s) {
    sv += gslice[base + s * BIN_SZ];
    mk |= (int)gmask[base + s * BIN_SZ];
  }
  int d = bin * BIN_SZ + tid;
  if (d < NDST && mk) {
    int node = ASS0 + d;
    float nv = mem[node] + sv;
    u2v lt = ltv[node];  // only this block ever writes this node's ltv
    if (lt.x == 255u) {  // first receipt: becomes working, fires next round
      u2v nl;
      nl.x = (unsigned)(r + 1);
      if (node < OUT0) {
        nl.y = __float_as_uint(tanhf(nv));  // snapshot at fire time
        ltv[node] = nl;
        mem[node] = 0.f;  // fired neurons erase memory
        newfront = 1;     // benign LDS race
      } else {
        nl.y = 0u;
        ltv[node] = nl;
        mem[node] = nv;  // outputs never fire, just accumulate
      }
    } else {
      mem[node] = nv;
    }
  }
  __syncthreads();
  if (tid == 0 && newfront) flags[r + 1] = 1;
}

// rounds 2..23 + output write, ONE cooperative kernel over survivors (or
// full bin regions if the survivor buffer overflowed). Uniform early break.
__global__ __launch_bounds__(1024) void kTail(
    int* flags, const int* __restrict__ bin_cursor,
    const u2v* __restrict__ csr, const u2v* __restrict__ ssur,
    const int* __restrict__ scur, float* __restrict__ mem,
    u2v* __restrict__ ltv, float* __restrict__ out, int cap, int scap) {
  cg::grid_group g = cg::this_grid();
  __shared__ float slice[BIN_SZ];
  __shared__ int smask[BIN_SZ];
  __shared__ int newfront;
  int tid = threadIdx.x;
  int bin = blockIdx.x;
  bool useS = (flags[30] == 0);
  int e0 = useS ? bin * scap : bin * cap;
  int e1 = useS ? min(scur[bin], bin * scap + scap) : bin_cursor[bin];
  const u2v* E = useS ? ssur : csr;
  for (int r = 2; r < NUM_ROUNDS; ++r) {
    if (flags[r] == 0) break;  // uniform across grid
    if (tid < BIN_SZ) {
      slice[tid] = 0.f;
      smask[tid] = 0;
    }
    if (tid == 0) newfront = 0;
    __syncthreads();
    unsigned rl = (unsigned)r;
    for (int e = e0 + tid; e < e1; e += 1024) {
      u2v q = E[e];
      u2v lt = ltv[(q.x & ~A0FLAG) >> BIN_SH];  // fallback path may see flags
      if (lt.x == rl) {
        atomicAdd(&slice[q.x & BIN_MK],
                  __uint_as_float(lt.y) * __uint_as_float(q.y));
        smask[q.x & BIN_MK] = 1;
      }
    }
    __syncthreads();
    if (tid < BIN_SZ) {
      int d = bin * BIN_SZ + tid;
      if (d < NDST && smask[tid]) {
        int node = ASS0 + d;
        float nv = mem[node] + slice[tid];
        u2v lt = ltv[node];
        if (lt.x == 255u) {
          u2v nl;
          nl.x = (unsigned)(r + 1);
          if (node < OUT0) {
            nl.y = __float_as_uint(tanhf(nv));
            ltv[node] = nl;
            mem[node] = 0.f;
            newfront = 1;
          } else {
            nl.y = 0u;
            ltv[node] = nl;
            mem[node] = nv;
          }
        } else {
          mem[node] = nv;
        }
      }
    }
    __syncthreads();
    if (tid == 0 && newfront) flags[r + 1] = 1;
    g.sync();
  }
  // output write (owning block wrote all mem for its dst range)
  if (tid < BIN_SZ) {
    int d = bin * BIN_SZ + tid;
    int node = ASS0 + d;
    if (d < NDST && node >= OUT0) out[node - OUT0] = tanhf(mem[node]);
  }
}

__global__ __launch_bounds__(256) void ko(const float* __restrict__ mem,
                                          float* __restrict__ out) {
  int i = blockIdx.x * 256 + threadIdx.x;
  if (i < OUT_F) out[i] = tanhf(mem[OUT0 + i]);
}

// ---------------------------------------------------------------------------
// Fallback dense multi-kernel path if ws too small.
// ---------------------------------------------------------------------------

__global__ __launch_bounds__(256) void k_init(float* mem, float* delta,
                                              int* status, int* got) {
  int i = blockIdx.x * 256 + threadIdx.x;
  if (i < TOTAL) {
    mem[i] = 0.f;
    delta[i] = 0.f;
    status[i] = 0;
    got[i] = 0;
  }
}
__global__ __launch_bounds__(256) void k_input(const float* __restrict__ x,
                                               const float* __restrict__ w,
                                               const int* __restrict__ src,
                                               const int* __restrict__ dst,
                                               int n, float* mem, int* got) {
  for (int e = blockIdx.x * 256 + threadIdx.x; e < n; e += gridDim.x * 256) {
    atomicAdd(&mem[dst[e]], x[src[e]] * w[e]);
    got[dst[e]] = 1;
  }
}
__global__ __launch_bounds__(256) void k_status0(int* status, int* got) {
  int i = blockIdx.x * 256 + threadIdx.x;
  if (i < TOTAL) {
    status[i] = got[i] ? 1 : 0;
    got[i] = 0;
  }
}
__global__ __launch_bounds__(256) void k_edge(const float* __restrict__ w,
                                              const int* __restrict__ src,
                                              const int* __restrict__ dst,
                                              int n,
                                              const float* __restrict__ mem,
                                              const int* __restrict__ status,
                                              float* delta, int* got) {
  for (int e = blockIdx.x * 256 + threadIdx.x; e < n; e += gridDim.x * 256) {
    int s = src[e];
    if (status[s] == 1) {
      atomicAdd(&delta[dst[e]], tanhf(mem[s]) * w[e]);
      got[dst[e]] = 1;
    }
  }
}
__global__ __launch_bounds__(256) void k_update(float* mem, float* delta,
                                                int* status, int* got) {
  int i = blockIdx.x * 256 + threadIdx.x;
  if (i < TOTAL) {
    int st = status[i];
    bool fire = (st == 1) && (i >= ASS0) && (i < OUT0);
    float d = delta[i];
    mem[i] = fire ? d : (mem[i] + d);
    status[i] = fire ? 2 : ((got[i] && st == 0) ? 1 : st);
    delta[i] = 0.f;
    got[i] = 0;
  }
}

extern "C" void kernel_launch(void* const* d_in, const int* in_sizes, int n_in,
                              void* d_out, int out_size, void* d_ws,
                              size_t ws_size, hipStream_t stream) {
  const float* x = (const float*)d_in[0];
  const float* iw = (const float*)d_in[1];
  const float* aw = (const float*)d_in[2];
  const int* ies = (const int*)d_in[3];
  const int* ied = (const int*)d_in[4];
  const int* aes = (const int*)d_in[5];
  const int* aed = (const int*)d_in[6];
  int E_in = in_sizes[1];
  int E_a = in_sizes[2];
  float* out = (float*)d_out;
  char* ws = (char*)d_ws;

  // fixed per-bin capacity: 1.3x mean, rounded to 256 (≈48 sigma margin)
  int cap = (((E_a / NBINS) * 13) / 10 + 255) & ~255;
  int scap = cap / 4;

  // layout: csr | ssur | ltv | mem | bin_cursor | scur | flags | bm |
  //         gslice | gmask
  size_t off_csr = 0;
  size_t off_ssur = off_csr + (size_t)NBINS * cap * 8;
  size_t off_ltv = off_ssur + (size_t)NBINS * scap * 8;
  size_t off_mem = off_ltv + (size_t)TOTAL * 8;
  size_t off_bcur = off_mem + (size_t)TOTAL * 4;
  size_t off_scur = off_bcur + (size_t)NBINS * 4;
  size_t off_flags = off_scur + (size_t)NBINS * 4;
  size_t off_bm = off_flags + 32 * 4;
  size_t off_gsl = off_bm + (size_t)NBM32 * 4;
  size_t off_gmk = off_gsl + (size_t)NBINS * SPLIT * BIN_SZ * 4;
  size_t need = off_gmk + (size_t)NBINS * SPLIT * BIN_SZ;

  if (ws_size >= need) {
    u2v* csr = (u2v*)(ws + off_csr);
    u2v* ssur = (u2v*)(ws + off_ssur);
    u2v* ltv = (u2v*)(ws + off_ltv);
    float* mem = (float*)(ws + off_mem);
    int* bin_cursor = (int*)(ws + off_bcur);
    int* scur = (int*)(ws + off_scur);
    int* flags = (int*)(ws + off_flags);
    unsigned* bm = (unsigned*)(ws + off_bm);
    float* gslice = (float*)(ws + off_gsl);
    char* gmask = ws + off_gmk;

    kz<<<(TOTAL + 255) / 256, 256, 0, stream>>>(mem, ltv, flags, bin_cursor,
                                                scur, bm, cap, scap);
    ki<<<(E_in + 255) / 256, 256, 0, stream>>>(x, iw, ies, ied, E_in, mem,
                                               (unsigned int*)ltv, bm);
    kp<<<(ASS + 255) / 256, 256, 0, stream>>>(mem, ltv);
    kc<<<NCON, CON_T, 0, stream>>>(aes, aed, aw, E_a, bin_cursor, bm, csr);

    for (int r = 0; r < 2; ++r) {
      kRe<<<NBINS * SPLIT, 256, 0, stream>>>(r, r == 1 ? 1 : 0, flags,
                                             bin_cursor, csr, ltv, gslice,
                                             gmask, ssur, scur, cap, scap);
      kRn<<<NBINS, 512, 0, stream>>>(r, flags, gslice, gmask, mem, ltv);
    }
    void* targs[] = {(void*)&flags, (void*)&bin_cursor, (void*)&csr,
                     (void*)&ssur,  (void*)&scur,       (void*)&mem,
                     (void*)&ltv,   (void*)&out,        (void*)&cap,
                     (void*)&scap};
    hipLaunchCooperativeKernel((void*)kTail, dim3(NBINS), dim3(1024), targs, 0,
                               stream);
    return;
  }

  // fallback: dense path
  float* mem = (float*)ws;
  float* delta = mem + TOTAL;
  int* status = (int*)(delta + TOTAL);
  int* got = status + TOTAL;
  const int nodeBlocks = (TOTAL + 255) / 256;
  k_init<<<nodeBlocks, 256, 0, stream>>>(mem, delta, status, got);
  int inBlocks = (E_in + 255) / 256;
  if (inBlocks > 1024) inBlocks = 1024;
  k_input<<<inBlocks, 256, 0, stream>>>(x, iw, ies, ied, E_in, mem, got);
  k_status0<<<nodeBlocks, 256, 0, stream>>>(status, got);
  int eBlocks = (E_a + 255) / 256;
  if (eBlocks > 2048) eBlocks = 2048;
  for (int r = 0; r < NUM_ROUNDS; ++r) {
    k_edge<<<eBlocks, 256, 0, stream>>>(aw, aes, aed, E_a, mem, status, delta,
                                        got);
    k_update<<<nodeBlocks, 256, 0, stream>>>(mem, delta, status, got);
  }
  ko<<<(OUT_F + 255) / 256, 256, 0, stream>>>(mem, out);
}